// Round 1
// baseline (1934.353 us; speedup 1.0000x reference)
//
#include <hip/hip_runtime.h>
#include <cstdint>

#define N_DATA 16384
#define DIM 512
#define MEM 512
#define KSEL 4096
#define NH 8
#define DH 64
#define KVDIM 1024
#define SCALE 0.125f
#define ZCNT 12288.0f
#define LN_EPS 1e-5f

// ---------- helpers ----------
__device__ __forceinline__ unsigned fenc(float x) {
    unsigned u = __float_as_uint(x);
    return (u & 0x80000000u) ? ~u : (u | 0x80000000u);
}

__device__ __forceinline__ float waveSum(float v) {
#pragma unroll
    for (int o = 32; o > 0; o >>= 1) v += __shfl_down(v, o, 64);
    return v;
}
__device__ __forceinline__ float waveMax(float v) {
#pragma unroll
    for (int o = 32; o > 0; o >>= 1) v = fmaxf(v, __shfl_down(v, o, 64));
    return v;
}
// blockDim.x == 256 assumed (4 waves)
__device__ float blockSum(float v) {
    __shared__ float sh[4];
    __syncthreads();
    v = waveSum(v);
    if ((threadIdx.x & 63) == 0) sh[threadIdx.x >> 6] = v;
    __syncthreads();
    if (threadIdx.x == 0) { float s = sh[0]; for (int i = 1; i < 4; ++i) s += sh[i]; sh[0] = s; }
    __syncthreads();
    return sh[0];
}
__device__ float blockMax(float v) {
    __shared__ float sh[4];
    __syncthreads();
    v = waveMax(v);
    if ((threadIdx.x & 63) == 0) sh[threadIdx.x >> 6] = v;
    __syncthreads();
    if (threadIdx.x == 0) { float s = sh[0]; for (int i = 1; i < 4; ++i) s = fmaxf(s, sh[i]); sh[0] = s; }
    __syncthreads();
    return sh[0];
}

// ---------- generic tiled fp32 GEMM ----------
// C[M x Nn] = alpha * A[M x K] (.) B  (+ bias)
// TRANSB: B is [Nn x K] row-major (NT GEMM, both operands K-contiguous)
// GATHER: A row index comes from gidx[]
// SIMMAX: instead of storing C, atomicMax(enc(rowmax(alpha*acc))) into simenc
// batching: blockIdx.z -> zs = z % zdiv (K-split), zh = z / zdiv (head)
template<int BM, int BN, int BK, int TM, int TN,
         bool TRANSB, bool GATHER, bool BIAS, bool SIMMAX, bool STOREC>
__global__ __launch_bounds__((BM / TM) * (BN / TN))
void gemm_k(const float* __restrict__ A, const float* __restrict__ B,
            const float* __restrict__ bias, const int* __restrict__ gidx,
            float* __restrict__ C, unsigned* __restrict__ simenc,
            int M, int Nn, int K, int lda, int ldb, int ldc,
            long zsA, long zsB, long zsC, int zdiv, long zsplitC, float alpha)
{
    constexpr int TX = BN / TN;
    constexpr int TY = BM / TM;
    constexpr int NT = TX * TY;
    __shared__ float As[BM * (BK + 1)];
    __shared__ float Bs[TRANSB ? (BN * (BK + 1)) : (BK * (BN + 1))];

    const int t = threadIdx.x;
    const int bm0 = blockIdx.x * BM;
    const int bn0 = blockIdx.y * BN;
    const int zs = (int)blockIdx.z % zdiv;
    const int zh = (int)blockIdx.z / zdiv;
    A += (long)zh * zsA;
    B += (long)zh * zsB;
    if (STOREC) C += (long)zh * zsC + (long)zs * zsplitC;

    const int tx = t % TX, ty = t / TX;
    float acc[TM][TN];
#pragma unroll
    for (int i = 0; i < TM; ++i)
#pragma unroll
        for (int j = 0; j < TN; ++j) acc[i][j] = 0.f;

    const int Kd = K / zdiv;
    const int kbeg = zs * Kd, kend = kbeg + Kd;
    for (int k0 = kbeg; k0 < kend; k0 += BK) {
        constexpr int AL = BM * BK / NT;
#pragma unroll
        for (int i = 0; i < AL; ++i) {
            int fid = i * NT + t;
            int m = fid / BK, kk = fid % BK;
            int row = bm0 + m;
            if (GATHER) row = gidx[row];
            As[m * (BK + 1) + kk] = A[(long)row * lda + (k0 + kk)];
        }
        if (TRANSB) {
            constexpr int BL = BN * BK / NT;
#pragma unroll
            for (int i = 0; i < BL; ++i) {
                int fid = i * NT + t;
                int n = fid / BK, kk = fid % BK;
                Bs[n * (BK + 1) + kk] = B[(long)(bn0 + n) * ldb + (k0 + kk)];
            }
        } else {
            constexpr int BL = BK * BN / NT;
#pragma unroll
            for (int i = 0; i < BL; ++i) {
                int fid = i * NT + t;
                int kk = fid / BN, n = fid % BN;
                Bs[kk * (BN + 1) + n] = B[(long)(k0 + kk) * ldb + (bn0 + n)];
            }
        }
        __syncthreads();
#pragma unroll
        for (int kk = 0; kk < BK; ++kk) {
            float a[TM], b[TN];
#pragma unroll
            for (int i = 0; i < TM; ++i) a[i] = As[(ty * TM + i) * (BK + 1) + kk];
#pragma unroll
            for (int j = 0; j < TN; ++j)
                b[j] = TRANSB ? Bs[(tx * TN + j) * (BK + 1) + kk]
                              : Bs[kk * (BN + 1) + (tx * TN + j)];
#pragma unroll
            for (int i = 0; i < TM; ++i)
#pragma unroll
                for (int j = 0; j < TN; ++j)
                    acc[i][j] = fmaf(a[i], b[j], acc[i][j]);
        }
        __syncthreads();
    }

    if (STOREC) {
#pragma unroll
        for (int i = 0; i < TM; ++i) {
            const int r = bm0 + ty * TM + i;
#pragma unroll
            for (int j = 0; j < TN; ++j) {
                const int c = bn0 + tx * TN + j;
                float v = alpha * acc[i][j];
                if (BIAS) v += bias[c];
                C[(long)r * ldc + c] = v;
            }
        }
    }
    if (SIMMAX) {
        __syncthreads();
        float* red = As;  // BM*TX <= BM*(BK+1)
#pragma unroll
        for (int i = 0; i < TM; ++i) {
            float mx = -3.0e38f;
#pragma unroll
            for (int j = 0; j < TN; ++j) mx = fmaxf(mx, alpha * acc[i][j]);
            red[(ty * TM + i) * TX + tx] = mx;
        }
        __syncthreads();
        if (t < BM) {
            float mx = red[t * TX];
#pragma unroll 4
            for (int x = 1; x < TX; ++x) mx = fmaxf(mx, red[t * TX + x]);
            atomicMax(simenc + bm0 + t, fenc(mx));
        }
    }
}

// ---------- exact top-k (k-th largest) via radix select on encoded keys ----------
#define SEL_T 1024
__global__ __launch_bounds__(SEL_T)
void select_topk(const unsigned* __restrict__ key, int* __restrict__ idxo, int n, int k)
{
    __shared__ unsigned hist[256];
    __shared__ unsigned sh_bin, sh_r;
    __shared__ unsigned tot[SEL_T];
    const int t = threadIdx.x;
    unsigned prefix = 0, mask = 0;
    unsigned r = (unsigned)k;
    for (int p = 3; p >= 0; --p) {
        if (t < 256) hist[t] = 0u;
        __syncthreads();
        for (int i = t; i < n; i += SEL_T) {
            unsigned kv = key[i];
            if ((kv & mask) == prefix)
                atomicAdd(&hist[(kv >> (p * 8)) & 255u], 1u);
        }
        __syncthreads();
        if (t == 0) {
            unsigned cum = 0;
            for (int b = 255; b >= 0; --b) {
                unsigned c = hist[b];
                if (cum + c >= r) { sh_bin = (unsigned)b; sh_r = r - cum; break; }
                cum += c;
            }
        }
        __syncthreads();
        prefix |= sh_bin << (p * 8);
        mask |= 255u << (p * 8);
        r = sh_r;
        __syncthreads();
    }
    const unsigned thr = prefix;
    const unsigned ties = r;  // take first `ties` keys == thr, by ascending index

    const int CH = n / SEL_T;
    const int base = t * CH;
    unsigned ceq = 0;
    for (int c = 0; c < CH; ++c) ceq += (key[base + c] == thr) ? 1u : 0u;
    tot[t] = ceq;
    __syncthreads();
    for (int off = 1; off < SEL_T; off <<= 1) {
        unsigned v = (t >= off) ? tot[t - off] : 0u;
        __syncthreads();
        tot[t] += v;
        __syncthreads();
    }
    const unsigned eqbase = (t > 0) ? tot[t - 1] : 0u;
    __syncthreads();
    unsigned eq = eqbase, csel = 0;
    for (int c = 0; c < CH; ++c) {
        unsigned kv = key[base + c];
        bool s;
        if (kv == thr) { s = (eq < ties); ++eq; }
        else s = (kv > thr);
        csel += s ? 1u : 0u;
    }
    tot[t] = csel;
    __syncthreads();
    for (int off = 1; off < SEL_T; off <<= 1) {
        unsigned v = (t >= off) ? tot[t - off] : 0u;
        __syncthreads();
        tot[t] += v;
        __syncthreads();
    }
    unsigned pos = (t > 0) ? tot[t - 1] : 0u;
    eq = eqbase;
    for (int c = 0; c < CH; ++c) {
        unsigned kv = key[base + c];
        bool s;
        if (kv == thr) { s = (eq < ties); ++eq; }
        else s = (kv > thr);
        if (s) idxo[pos++] = base + c;
    }
}

// ---------- attention softmax over 4096 selected keys + 12288 implicit zeros ----------
__global__ __launch_bounds__(256)
void softmax_att(float* __restrict__ att)
{
    float* row = att + (long)blockIdx.x * KSEL;
    const int t = threadIdx.x;
    float v[16];
    float mx = -3.0e38f;
#pragma unroll
    for (int i = 0; i < 16; ++i) { v[i] = row[t + (i << 8)]; mx = fmaxf(mx, v[i]); }
    mx = blockMax(mx);
    const float m = fmaxf(mx, 0.f);  // unselected keys contribute score 0
    float s = 0.f;
#pragma unroll
    for (int i = 0; i < 16; ++i) { v[i] = expf(v[i] - m); s += v[i]; }
    s = blockSum(s);
    const float inv = 1.f / (s + ZCNT * expf(-m));
#pragma unroll
    for (int i = 0; i < 16; ++i) row[t + (i << 8)] = v[i] * inv;
}

// ---------- reduce split-K PV partials: o[m][h*64+d] = sum_sp oP[sp][h][m][d] ----------
__global__ __launch_bounds__(256)
void pv_reduce(const float* __restrict__ oP, float* __restrict__ o)
{
    const int i = blockIdx.x * 256 + threadIdx.x;  // over 512*512
    const int m = i >> 9;
    const int hd = i & 511;
    const int h = hd >> 6, d = hd & 63;
    float s = 0.f;
#pragma unroll
    for (int sp = 0; sp < 4; ++sp)
        s += oP[((long)(sp * 8 + h) * 512 + m) * 64 + d];
    o[i] = s;
}

// ---------- residual add + LayerNorm (no affine) ----------
__global__ __launch_bounds__(256)
void ln_add_k(const float* __restrict__ outp, const float* __restrict__ Min,
              float* __restrict__ Mout)
{
    const int r = blockIdx.x;
    const int t = threadIdx.x;
    float x0 = outp[r * DIM + t] + Min[r * DIM + t];
    float x1 = outp[r * DIM + t + 256] + Min[r * DIM + t + 256];
    float s = blockSum(x0 + x1);
    float s2 = blockSum(x0 * x0 + x1 * x1);
    const float mu = s * (1.f / DIM);
    const float var = s2 * (1.f / DIM) - mu * mu;
    const float rs = rsqrtf(var + LN_EPS);
    Mout[r * DIM + t] = (x0 - mu) * rs;
    Mout[r * DIM + t + 256] = (x1 - mu) * rs;
}

// ---------- final log-softmax: writes p in place, sim, lse, max-logp ----------
__global__ __launch_bounds__(256)
void emb_softmax(float* __restrict__ logits, float* __restrict__ simout,
                 float* __restrict__ lse, float* __restrict__ mlp)
{
    const int r = blockIdx.x;
    float* row = logits + (long)r * MEM;
    const int t = threadIdx.x;
    float a = row[t], b = row[t + 256];
    float mx = blockMax(fmaxf(a, b));
    float s = blockSum(expf(a - mx) + expf(b - mx));
    float l = mx + logf(s);
    if (t == 0) { simout[r] = mx; lse[r] = l; mlp[r] = mx - l; }
    row[t] = expf(a - l);
    row[t + 256] = expf(b - l);
}

// ---------- deterministic scalar losses ----------
__global__ __launch_bounds__(256)
void reduce_loss(const float* __restrict__ lse, const float* __restrict__ mlp,
                 float* __restrict__ o2)
{
    const int t = threadIdx.x;
    float s1 = 0.f, s2 = 0.f;
    for (int i = t; i < N_DATA; i += 256) { s1 += mlp[i]; float l = lse[i]; s2 += l * l; }
    s1 = blockSum(s1);
    s2 = blockSum(s2);
    if (t == 0) { o2[0] = -s1 * (1.f / N_DATA); o2[1] = s2 * (1.f / N_DATA); }
}

// ---------- host orchestration ----------
extern "C" void kernel_launch(void* const* d_in, const int* in_sizes, int n_in,
                              void* d_out, int out_size, void* d_ws, size_t ws_size,
                              hipStream_t stream)
{
    (void)in_sizes; (void)n_in; (void)out_size; (void)ws_size;
    const float* data   = (const float*)d_in[0];
    const float* Memory = (const float*)d_in[1];
    const float* Wkv    = (const float*)d_in[2];
    const float* Wq     = (const float*)d_in[3];
    const float* Wm     = (const float*)d_in[4];
    const float* bm     = (const float*)d_in[5];
    float* out = (float*)d_out;

    char* w = (char*)d_ws;
    unsigned* simenc = (unsigned*)(w);                         // 64 KB
    int*   idx   = (int*)  (w + 65536);                        // 16 KB
    float* Ma    = (float*)(w + 81920);                        // 1 MB
    float* Mb    = (float*)(w + 81920 + 1 * 1048576);          // 1 MB
    float* q     = (float*)(w + 81920 + 2 * 1048576);          // 1 MB
    float* o     = (float*)(w + 81920 + 3 * 1048576);          // 1 MB
    float* outp  = (float*)(w + 81920 + 4 * 1048576);          // 1 MB
    float* oP    = (float*)(w + 81920 + 5 * 1048576);          // 4 MB
    float* lse   = (float*)(w + 81920 + 9 * 1048576);          // 64 KB
    float* mlp   = (float*)(w + 81920 + 9 * 1048576 + 65536);  // 64 KB
    float* kvsel = (float*)(w + 81920 + 9 * 1048576 + 131072); // 16 MB
    float* att   = (float*)(w + 81920 + 25 * 1048576 + 131072);// 64 MB (logits aliases)
    float* logits = att;

    // sim (row-max of data@M^T * scale) -> top-k select -> kv projection of selected rows
    auto sim_select_kv = [&](const float* Mrows) {
        hipMemsetAsync(simenc, 0, N_DATA * 4, stream);
        gemm_k<128,128,16,8,8, true,false,false,true,false><<<dim3(128,4,1),256,0,stream>>>(
            data, Mrows, nullptr, nullptr, nullptr, simenc,
            N_DATA, MEM, DIM, DIM, DIM, 0, 0, 0, 0, 1, 0, SCALE);
        select_topk<<<1, SEL_T, 0, stream>>>(simenc, idx, N_DATA, KSEL);
        gemm_k<128,128,16,8,8, false,true,false,false,true><<<dim3(32,8,1),256,0,stream>>>(
            data, Wkv, nullptr, idx, kvsel, nullptr,
            KSEL, KVDIM, DIM, DIM, KVDIM, KVDIM, 0, 0, 0, 1, 0, 1.0f);
    };

    auto cross = [&](const float* Mcur, float* Mnext, int l) {
        // q = Mcur @ Wq[l]
        gemm_k<64,64,16,4,4, false,false,false,false,true><<<dim3(8,8,1),256,0,stream>>>(
            Mcur, Wq + (long)l * DIM * DIM, nullptr, nullptr, q, nullptr,
            DIM, DIM, DIM, DIM, DIM, DIM, 0, 0, 0, 1, 0, 1.0f);
        // scores[h][m][j] = scale * q_h[m] . k_h[j]   (batched over heads via z)
        gemm_k<128,128,16,8,8, true,false,false,false,true><<<dim3(4,32,NH),256,0,stream>>>(
            q, kvsel, nullptr, nullptr, att, nullptr,
            DIM, KSEL, DH, DIM, KVDIM, KSEL,
            (long)DH, (long)DH, (long)DIM * KSEL, 1, 0, SCALE);
        softmax_att<<<NH * DIM, 256, 0, stream>>>(att);
        // o_partial = att @ v   (split-K x4 for parallelism)
        gemm_k<64,64,16,4,4, false,false,false,false,true><<<dim3(8,1,NH*4),256,0,stream>>>(
            att, kvsel + DIM, nullptr, nullptr, oP, nullptr,
            DIM, DH, KSEL, KSEL, KVDIM, DH,
            (long)DIM * KSEL, (long)DH, (long)DIM * DH, 4, (long)NH * DIM * DH, 1.0f);
        pv_reduce<<<1024, 256, 0, stream>>>(oP, o);
        // out = o @ Wm[l] + bm[l]
        gemm_k<64,64,16,4,4, false,false,true,false,true><<<dim3(8,8,1),256,0,stream>>>(
            o, Wm + (long)l * DIM * DIM, bm + l * DIM, nullptr, outp, nullptr,
            DIM, DIM, DIM, DIM, DIM, DIM, 0, 0, 0, 1, 0, 1.0f);
        ln_add_k<<<DIM, 256, 0, stream>>>(outp, Mcur, Mnext);
    };

    const float* Mcur = Memory;
    float* Mnext = Ma;
    sim_select_kv(Mcur);
    for (int t = 0; t < 2; ++t) {
        for (int l = 0; l < 2; ++l) {
            cross(Mcur, Mnext, l);
            Mcur = Mnext;
            Mnext = (Mcur == Ma) ? Mb : Ma;
        }
        if (t == 0) sim_select_kv(Mcur);
    }

    // final: logits = scale * data @ M^T  (stored), then softmax/emb/losses
    gemm_k<128,128,16,8,8, true,false,false,false,true><<<dim3(128,4,1),256,0,stream>>>(
        data, Mcur, nullptr, nullptr, logits, nullptr,
        N_DATA, MEM, DIM, DIM, DIM, MEM, 0, 0, 0, 1, 0, SCALE);
    emb_softmax<<<N_DATA, 256, 0, stream>>>(logits, out, lse, mlp);
    // out_ebs = p @ M
    gemm_k<128,128,16,8,8, false,false,false,false,true><<<dim3(128,4,1),256,0,stream>>>(
        logits, Mcur, nullptr, nullptr, out + N_DATA, nullptr,
        N_DATA, DIM, MEM, MEM, DIM, DIM, 0, 0, 0, 1, 0, 1.0f);
    reduce_loss<<<1, 256, 0, stream>>>(lse, mlp, out + N_DATA + (long)N_DATA * DIM);
}

// Round 2
// 646.442 us; speedup vs baseline: 2.9923x; 2.9923x over previous
//
#include <hip/hip_runtime.h>
#include <cstdint>

#define N_DATA 16384
#define DIM 512
#define MEM 512
#define KSEL 4096
#define NH 8
#define DH 64
#define KVDIM 1024
#define SCALE 0.125f
#define ZCNT 12288.0f
#define LN_EPS 1e-5f

typedef unsigned short u16;
using short8 = __attribute__((ext_vector_type(8))) short;
using f32x4  = __attribute__((ext_vector_type(4))) float;

// ---------- scalar helpers ----------
__device__ __forceinline__ unsigned fenc(float x) {
    unsigned u = __float_as_uint(x);
    return (u & 0x80000000u) ? ~u : (u | 0x80000000u);
}
__device__ __forceinline__ u16 f2bf(float x) {          // RNE f32 -> bf16
    unsigned u = __float_as_uint(x);
    u += 0x7fffu + ((u >> 16) & 1u);
    return (u16)(u >> 16);
}
__device__ __forceinline__ float bf2f(u16 h) { return __uint_as_float(((unsigned)h) << 16); }

__device__ __forceinline__ float waveSum(float v) {
#pragma unroll
    for (int o = 32; o > 0; o >>= 1) v += __shfl_down(v, o, 64);
    return v;
}
__device__ __forceinline__ float waveMax(float v) {
#pragma unroll
    for (int o = 32; o > 0; o >>= 1) v = fmaxf(v, __shfl_down(v, o, 64));
    return v;
}
// blockDim.x == 256 assumed (4 waves)
__device__ float blockSum(float v) {
    __shared__ float sh[4];
    __syncthreads();
    v = waveSum(v);
    if ((threadIdx.x & 63) == 0) sh[threadIdx.x >> 6] = v;
    __syncthreads();
    if (threadIdx.x == 0) { float s = sh[0]; for (int i = 1; i < 4; ++i) s += sh[i]; sh[0] = s; }
    __syncthreads();
    return sh[0];
}
__device__ float blockMax(float v) {
    __shared__ float sh[4];
    __syncthreads();
    v = waveMax(v);
    if ((threadIdx.x & 63) == 0) sh[threadIdx.x >> 6] = v;
    __syncthreads();
    if (threadIdx.x == 0) { float s = sh[0]; for (int i = 1; i < 4; ++i) s = fmaxf(s, sh[i]); sh[0] = s; }
    __syncthreads();
    return sh[0];
}

// ---------- global -> LDS async staging of a ROWS x 32 bf16 tile ----------
// LDS layout linear [ROWS][32] bf16. NW waves cooperate; each inst moves 1 KiB.
template<int ROWS, int NW, bool GATHER>
__device__ __forceinline__ void stage_tile(const u16* __restrict__ src, int ld, int k0,
                                           int row0, const int* __restrict__ gidx,
                                           u16* lds, int wave)
{
    constexpr int NI = ROWS / 16;       // 1KiB instructions for the whole tile
    const int lane = threadIdx.x & 63;
#pragma unroll
    for (int i = wave; i < NI; i += NW) {
        const int ch = i * 64 + lane;   // 16B chunk id
        const int r = ch >> 2, cc = ch & 3;
        int rg = row0 + r;
        if (GATHER) rg = gidx[rg];
        const u16* g = src + (long)rg * ld + k0 + cc * 8;
        u16* l = lds + i * 512;         // wave-uniform base; HW adds lane*16
        __builtin_amdgcn_global_load_lds((const __attribute__((address_space(1))) void*)g,
                                         (__attribute__((address_space(3))) void*)l,
                                         16, 0, 0);
    }
}

// ---------- bf16 MFMA GEMM: C[M x N] = alpha * A[M x K] * B[N x K]^T (+ bias) ----------
// EPI: 0 = store fp32, 1 = store bf16, 2 = rowmax atomic into simenc (no store)
// batching: blockIdx.z -> zs = z % zdiv (K split), zh = z / zdiv (head)
template<int WM, int WN, bool GATHER, int EPI, bool BIAS>
__global__ __launch_bounds__(WM * WN * 64)
void mfma_gemm(const u16* __restrict__ A, const u16* __restrict__ B,
               const float* __restrict__ bias, const int* __restrict__ gidx,
               void* __restrict__ Cv, unsigned* __restrict__ simenc,
               int K, int lda, int ldb, int ldc,
               long zsA, long zsB, long zsC, int zdiv, long zsplitC, float alpha)
{
    constexpr int BM = WM * 64, BN = WN * 64, NW = WM * WN;
    __shared__ __align__(16) u16 As[BM * 32];
    __shared__ __align__(16) u16 Bs[BN * 32];

    const int t = threadIdx.x;
    const int wave = t >> 6, lane = t & 63;
    const int wr = wave / WN, wc = wave % WN;
    const int l15 = lane & 15, l4 = lane >> 4;
    const int bm0 = blockIdx.x * BM, bn0 = blockIdx.y * BN;
    const int zs = (int)blockIdx.z % zdiv;
    const int zh = (int)blockIdx.z / zdiv;
    A += (long)zh * zsA;
    B += (long)zh * zsB;

    f32x4 acc[4][4];
#pragma unroll
    for (int i = 0; i < 4; ++i)
#pragma unroll
        for (int j = 0; j < 4; ++j)
#pragma unroll
            for (int r = 0; r < 4; ++r) acc[i][j][r] = 0.f;

    const int Kd = K / zdiv;
    const int kbeg = zs * Kd;
    for (int k0 = kbeg; k0 < kbeg + Kd; k0 += 32) {
        stage_tile<BM, NW, GATHER>(A, lda, k0, bm0, gidx, As, wave);
        stage_tile<BN, NW, false>(B, ldb, k0, bn0, nullptr, Bs, wave);
        __syncthreads();
        short8 a[4], b[4];
#pragma unroll
        for (int fm = 0; fm < 4; ++fm)
            a[fm] = *(const short8*)(As + (wr * 64 + fm * 16 + l15) * 32 + l4 * 8);
#pragma unroll
        for (int fn = 0; fn < 4; ++fn)
            b[fn] = *(const short8*)(Bs + (wc * 64 + fn * 16 + l15) * 32 + l4 * 8);
#pragma unroll
        for (int fm = 0; fm < 4; ++fm)
#pragma unroll
            for (int fn = 0; fn < 4; ++fn)
                acc[fm][fn] = __builtin_amdgcn_mfma_f32_16x16x32_bf16(a[fm], b[fn], acc[fm][fn], 0, 0, 0);
        __syncthreads();
    }

    if (EPI == 2) {
#pragma unroll
        for (int fm = 0; fm < 4; ++fm)
#pragma unroll
            for (int r = 0; r < 4; ++r) {
                float mx = acc[fm][0][r];
#pragma unroll
                for (int fn = 1; fn < 4; ++fn) mx = fmaxf(mx, acc[fm][fn][r]);
#pragma unroll
                for (int o = 8; o >= 1; o >>= 1) mx = fmaxf(mx, __shfl_xor(mx, o, 64));
                if (l15 == 0) {
                    const int row = bm0 + wr * 64 + fm * 16 + l4 * 4 + r;
                    atomicMax(simenc + row, fenc(alpha * mx));
                }
            }
    } else if (EPI == 0) {
        float* C = (float*)Cv + (long)zh * zsC + (long)zs * zsplitC;
#pragma unroll
        for (int fm = 0; fm < 4; ++fm)
#pragma unroll
            for (int fn = 0; fn < 4; ++fn)
#pragma unroll
                for (int r = 0; r < 4; ++r) {
                    const int row = bm0 + wr * 64 + fm * 16 + l4 * 4 + r;
                    const int col = bn0 + wc * 64 + fn * 16 + l15;
                    float v = alpha * acc[fm][fn][r];
                    if (BIAS) v += bias[col];
                    C[(long)row * ldc + col] = v;
                }
    } else {
        u16* C = (u16*)Cv + (long)zh * zsC + (long)zs * zsplitC;
#pragma unroll
        for (int fm = 0; fm < 4; ++fm)
#pragma unroll
            for (int fn = 0; fn < 4; ++fn)
#pragma unroll
                for (int r = 0; r < 4; ++r) {
                    const int row = bm0 + wr * 64 + fm * 16 + l4 * 4 + r;
                    const int col = bn0 + wc * 64 + fn * 16 + l15;
                    float v = alpha * acc[fm][fn][r];
                    if (BIAS) v += bias[col];
                    C[(long)row * ldc + col] = f2bf(v);
                }
    }
}

// ---------- fp32 -> bf16 convert ----------
__global__ __launch_bounds__(256)
void conv_f32_bf(const float* __restrict__ s, u16* __restrict__ d, int n)
{
    const int i = (blockIdx.x * 256 + threadIdx.x) * 4;
    if (i >= n) return;
    const float4 v = *(const float4*)(s + i);
    ushort4 o;
    o.x = f2bf(v.x); o.y = f2bf(v.y); o.z = f2bf(v.z); o.w = f2bf(v.w);
    *(ushort4*)(d + i) = o;
}

// ---------- transpose (fp32 or bf16 in) -> bf16 out: D[c][r] = S[r][c] ----------
template<bool INBF>
__global__ __launch_bounds__(256)
void transpose_bf(const void* __restrict__ Sv, u16* __restrict__ D,
                  int Rr, int Cc, int ldS)
{
    __shared__ float tile[32][33];
    const int c0 = blockIdx.x * 32, r0 = blockIdx.y * 32;
    const int tx = threadIdx.x & 31, ty = threadIdx.x >> 5; // ty 0..7
#pragma unroll
    for (int j = 0; j < 32; j += 8) {
        const int r = r0 + ty + j, c = c0 + tx;
        float v = INBF ? bf2f(((const u16*)Sv)[(long)r * ldS + c])
                       : ((const float*)Sv)[(long)r * ldS + c];
        tile[ty + j][tx] = v;
    }
    __syncthreads();
#pragma unroll
    for (int j = 0; j < 32; j += 8) {
        const int cO = c0 + ty + j, rO = r0 + tx;
        D[(long)cO * Rr + rO] = f2bf(tile[tx][ty + j]);
    }
}

// ---------- exact top-k via radix select on encoded keys (unchanged, verified) ----------
#define SEL_T 1024
__global__ __launch_bounds__(SEL_T)
void select_topk(const unsigned* __restrict__ key, int* __restrict__ idxo, int n, int k)
{
    __shared__ unsigned hist[256];
    __shared__ unsigned sh_bin, sh_r;
    __shared__ unsigned tot[SEL_T];
    const int t = threadIdx.x;
    unsigned prefix = 0, mask = 0;
    unsigned r = (unsigned)k;
    for (int p = 3; p >= 0; --p) {
        if (t < 256) hist[t] = 0u;
        __syncthreads();
        for (int i = t; i < n; i += SEL_T) {
            unsigned kv = key[i];
            if ((kv & mask) == prefix)
                atomicAdd(&hist[(kv >> (p * 8)) & 255u], 1u);
        }
        __syncthreads();
        if (t == 0) {
            unsigned cum = 0;
            for (int b = 255; b >= 0; --b) {
                unsigned c = hist[b];
                if (cum + c >= r) { sh_bin = (unsigned)b; sh_r = r - cum; break; }
                cum += c;
            }
        }
        __syncthreads();
        prefix |= sh_bin << (p * 8);
        mask |= 255u << (p * 8);
        r = sh_r;
        __syncthreads();
    }
    const unsigned thr = prefix;
    const unsigned ties = r;

    const int CH = n / SEL_T;
    const int base = t * CH;
    unsigned ceq = 0;
    for (int c = 0; c < CH; ++c) ceq += (key[base + c] == thr) ? 1u : 0u;
    tot[t] = ceq;
    __syncthreads();
    for (int off = 1; off < SEL_T; off <<= 1) {
        unsigned v = (t >= off) ? tot[t - off] : 0u;
        __syncthreads();
        tot[t] += v;
        __syncthreads();
    }
    const unsigned eqbase = (t > 0) ? tot[t - 1] : 0u;
    __syncthreads();
    unsigned eq = eqbase, csel = 0;
    for (int c = 0; c < CH; ++c) {
        unsigned kv = key[base + c];
        bool s;
        if (kv == thr) { s = (eq < ties); ++eq; }
        else s = (kv > thr);
        csel += s ? 1u : 0u;
    }
    tot[t] = csel;
    __syncthreads();
    for (int off = 1; off < SEL_T; off <<= 1) {
        unsigned v = (t >= off) ? tot[t - off] : 0u;
        __syncthreads();
        tot[t] += v;
        __syncthreads();
    }
    unsigned pos = (t > 0) ? tot[t - 1] : 0u;
    eq = eqbase;
    for (int c = 0; c < CH; ++c) {
        unsigned kv = key[base + c];
        bool s;
        if (kv == thr) { s = (eq < ties); ++eq; }
        else s = (kv > thr);
        if (s) idxo[pos++] = base + c;
    }
}

// ---------- attention softmax over 4096 selected keys + 12288 implicit zeros ----------
// in-place on bf16 rows; one block per row (8 h * 512 m rows)
__global__ __launch_bounds__(256)
void softmax_att_bf(u16* __restrict__ att)
{
    u16* row = att + (long)blockIdx.x * KSEL;
    const int t = threadIdx.x;
    short8 w0 = *(const short8*)(row + t * 16);
    short8 w1 = *(const short8*)(row + t * 16 + 8);
    float v[16];
    float mx = -3.0e38f;
#pragma unroll
    for (int j = 0; j < 8; ++j) { v[j] = bf2f((u16)w0[j]); v[8 + j] = bf2f((u16)w1[j]); }
#pragma unroll
    for (int j = 0; j < 16; ++j) mx = fmaxf(mx, v[j]);
    mx = blockMax(mx);
    const float m = fmaxf(mx, 0.f);           // unselected keys have score exactly 0
    float s = 0.f;
#pragma unroll
    for (int j = 0; j < 16; ++j) { v[j] = __expf(v[j] - m); s += v[j]; }
    s = blockSum(s);
    const float inv = 1.f / (s + ZCNT * __expf(-m));
#pragma unroll
    for (int j = 0; j < 8; ++j) { w0[j] = (short)f2bf(v[j] * inv); w1[j] = (short)f2bf(v[8 + j] * inv); }
    *(short8*)(row + t * 16) = w0;
    *(short8*)(row + t * 16 + 8) = w1;
}

// ---------- reduce split-K PV partials into bf16 o[m][h*64+d] ----------
__global__ __launch_bounds__(256)
void pv_reduce(const float* __restrict__ oP, u16* __restrict__ o)
{
    const int i = blockIdx.x * 256 + threadIdx.x;   // over 512*512
    float s = 0.f;
#pragma unroll
    for (int sp = 0; sp < 4; ++sp) s += oP[sp * (DIM * DIM) + i];
    o[i] = f2bf(s);
}

// ---------- residual add + LayerNorm (fp32) ----------
__global__ __launch_bounds__(256)
void ln_add_k(const float* __restrict__ outp, const float* __restrict__ Min,
              float* __restrict__ Mout)
{
    const int r = blockIdx.x;
    const int t = threadIdx.x;
    float x0 = outp[r * DIM + t] + Min[r * DIM + t];
    float x1 = outp[r * DIM + t + 256] + Min[r * DIM + t + 256];
    float s = blockSum(x0 + x1);
    float s2 = blockSum(x0 * x0 + x1 * x1);
    const float mu = s * (1.f / DIM);
    const float var = s2 * (1.f / DIM) - mu * mu;
    const float rs = rsqrtf(var + LN_EPS);
    Mout[r * DIM + t] = (x0 - mu) * rs;
    Mout[r * DIM + t + 256] = (x1 - mu) * rs;
}

// ---------- final log-softmax on bf16 logits; writes p (bf16, in place), sim, lse, mlp ----------
__global__ __launch_bounds__(256)
void emb_softmax_bf(u16* __restrict__ logits, float* __restrict__ simout,
                    float* __restrict__ lse, float* __restrict__ mlp)
{
    const int r = blockIdx.x;
    u16* row = logits + (long)r * MEM;
    const int t = threadIdx.x;
    unsigned w = *(const unsigned*)(row + 2 * t);
    float a = bf2f((u16)(w & 0xffffu)), b = bf2f((u16)(w >> 16));
    float mx = blockMax(fmaxf(a, b));
    float s = blockSum(__expf(a - mx) + __expf(b - mx));
    float l = mx + __logf(s);
    if (t == 0) { simout[r] = mx; lse[r] = l; mlp[r] = mx - l; }
    unsigned o = (unsigned)f2bf(__expf(a - l)) | ((unsigned)f2bf(__expf(b - l)) << 16);
    *(unsigned*)(row + 2 * t) = o;
}

// ---------- deterministic scalar losses ----------
__global__ __launch_bounds__(256)
void reduce_loss(const float* __restrict__ lse, const float* __restrict__ mlp,
                 float* __restrict__ o2)
{
    const int t = threadIdx.x;
    float s1 = 0.f, s2 = 0.f;
    for (int i = t; i < N_DATA; i += 256) { s1 += mlp[i]; float l = lse[i]; s2 += l * l; }
    s1 = blockSum(s1);
    s2 = blockSum(s2);
    if (t == 0) { o2[0] = -s1 * (1.f / N_DATA); o2[1] = s2 * (1.f / N_DATA); }
}

// ---------- host orchestration ----------
extern "C" void kernel_launch(void* const* d_in, const int* in_sizes, int n_in,
                              void* d_out, int out_size, void* d_ws, size_t ws_size,
                              hipStream_t stream)
{
    (void)in_sizes; (void)n_in; (void)out_size; (void)ws_size;
    const float* data   = (const float*)d_in[0];
    const float* Memory = (const float*)d_in[1];
    const float* Wkv    = (const float*)d_in[2];
    const float* Wq     = (const float*)d_in[3];
    const float* Wm     = (const float*)d_in[4];
    const float* bm     = (const float*)d_in[5];
    float* out = (float*)d_out;

    char* w = (char*)d_ws;
    unsigned* simenc = (unsigned*)(w + 0);             // 64K
    int*   idx     = (int*)  (w + 65536);              // 16K
    float* lse     = (float*)(w + 81920);              // 64K
    float* mlp     = (float*)(w + 147456);             // 64K
    float* Ma      = (float*)(w + 262144);             // 1M
    float* Mb      = (float*)(w + 1310720);            // 1M
    u16*   Mc_bf   = (u16*)  (w + 2359296);            // 512K
    u16*   MT_bf   = (u16*)  (w + 2883584);            // 512K
    u16*   WqT_bf  = (u16*)  (w + 3407872);            // 1M (2 layers)
    u16*   WmT_bf  = (u16*)  (w + 4456448);            // 1M
    u16*   WkvT_bf = (u16*)  (w + 5505024);            // 1M
    u16*   q_bf    = (u16*)  (w + 6553600);            // 512K
    u16*   o_bf    = (u16*)  (w + 7077888);            // 512K
    float* outp    = (float*)(w + 7602176);            // 1M
    u16*   data_bf = (u16*)  (w + 8650752);            // 16M
    u16*   kvsel_bf= (u16*)  (w + 25427968);           // 8M  [4096][1024]
    u16*   vT_bf   = (u16*)  (w + 33816576);           // 4M  [8*64][4096]
    float* oP      = (float*)(w + 38010880);           // 4M  [4][512][512]
    u16*   att_bf  = (u16*)  (w + 42205184);           // 32M [8][512][4096]; logits/p alias
    u16*   logits_bf = att_bf;

    // one-time conversions
    conv_f32_bf<<<(N_DATA * DIM / 4 + 255) / 256, 256, 0, stream>>>(data, data_bf, N_DATA * DIM);
    transpose_bf<false><<<dim3(KVDIM / 32, DIM / 32), 256, 0, stream>>>(Wkv, WkvT_bf, DIM, KVDIM, KVDIM);
    for (int l = 0; l < 2; ++l) {
        transpose_bf<false><<<dim3(16, 16), 256, 0, stream>>>(Wq + (long)l * DIM * DIM, WqT_bf + (long)l * DIM * DIM, DIM, DIM, DIM);
        transpose_bf<false><<<dim3(16, 16), 256, 0, stream>>>(Wm + (long)l * DIM * DIM, WmT_bf + (long)l * DIM * DIM, DIM, DIM, DIM);
    }

    // sim (rowmax of scale*data@M^T) -> top-k -> kv projection of selected rows -> v transpose
    auto sim_select_kv = [&](const float* Mrows) {
        conv_f32_bf<<<(DIM * DIM / 4 + 255) / 256, 256, 0, stream>>>(Mrows, Mc_bf, DIM * DIM);
        hipMemsetAsync(simenc, 0, N_DATA * 4, stream);
        mfma_gemm<2, 2, false, 2, false><<<dim3(128, 4, 1), 256, 0, stream>>>(
            data_bf, Mc_bf, nullptr, nullptr, nullptr, simenc,
            DIM, DIM, DIM, 0, 0, 0, 0, 1, 0, SCALE);
        select_topk<<<1, SEL_T, 0, stream>>>(simenc, idx, N_DATA, KSEL);
        mfma_gemm<2, 2, true, 1, false><<<dim3(32, 8, 1), 256, 0, stream>>>(
            data_bf, WkvT_bf, nullptr, idx, kvsel_bf, nullptr,
            DIM, DIM, DIM, KVDIM, 0, 0, 0, 1, 0, 1.0f);
        transpose_bf<true><<<dim3(DIM / 32, KSEL / 32), 256, 0, stream>>>(
            kvsel_bf + DIM, vT_bf, KSEL, DIM, KVDIM);
    };

    auto cross = [&](const float* Mcur, float* Mnext, int l) {
        conv_f32_bf<<<(DIM * DIM / 4 + 255) / 256, 256, 0, stream>>>(Mcur, Mc_bf, DIM * DIM);
        // q = Mcur @ Wq[l]  (bf16 out)
        mfma_gemm<2, 2, false, 1, false><<<dim3(4, 4, 1), 256, 0, stream>>>(
            Mc_bf, WqT_bf + (long)l * DIM * DIM, nullptr, nullptr, q_bf, nullptr,
            DIM, DIM, DIM, DIM, 0, 0, 0, 1, 0, 1.0f);
        // scores: per head, scale * q_h @ k_h^T -> bf16 att
        mfma_gemm<2, 2, false, 1, false><<<dim3(4, 32, NH), 256, 0, stream>>>(
            q_bf, kvsel_bf, nullptr, nullptr, att_bf, nullptr,
            DH, DIM, KVDIM, KSEL, DH, DH, (long)DIM * KSEL, 1, 0, SCALE);
        softmax_att_bf<<<NH * DIM, 256, 0, stream>>>(att_bf);
        // o partials: att_h @ v_h  (split-K x4)
        mfma_gemm<2, 1, false, 0, false><<<dim3(4, 1, NH * 4), 128, 0, stream>>>(
            att_bf, vT_bf, nullptr, nullptr, oP, nullptr,
            KSEL, KSEL, KSEL, DIM, (long)DIM * KSEL, (long)DH * KSEL, DH, 4, (long)DIM * DIM, 1.0f);
        pv_reduce<<<DIM * DIM / 256, 256, 0, stream>>>(oP, o_bf);
        // out = o @ Wm[l] + bm[l] (fp32 out)
        mfma_gemm<2, 2, false, 0, true><<<dim3(4, 4, 1), 256, 0, stream>>>(
            o_bf, WmT_bf + (long)l * DIM * DIM, bm + (long)l * DIM, nullptr, outp, nullptr,
            DIM, DIM, DIM, DIM, 0, 0, 0, 1, 0, 1.0f);
        ln_add_k<<<DIM, 256, 0, stream>>>(outp, Mcur, Mnext);
    };

    const float* Mcur = Memory;
    float* Mnext = Ma;
    sim_select_kv(Mcur);
    for (int it = 0; it < 2; ++it) {
        for (int l = 0; l < 2; ++l) {
            cross(Mcur, Mnext, l);
            Mcur = Mnext;
            Mnext = (Mcur == Ma) ? Mb : Ma;
        }
        if (it == 0) sim_select_kv(Mcur);
    }

    // final: logits (bf16) = scale * data @ M^T ; softmax/emb/losses; out_ebs = p @ M
    conv_f32_bf<<<(DIM * DIM / 4 + 255) / 256, 256, 0, stream>>>(Mcur, Mc_bf, DIM * DIM);
    mfma_gemm<2, 2, false, 1, false><<<dim3(128, 4, 1), 256, 0, stream>>>(
        data_bf, Mc_bf, nullptr, nullptr, logits_bf, nullptr,
        DIM, DIM, DIM, MEM, 0, 0, 0, 1, 0, SCALE);
    emb_softmax_bf<<<N_DATA, 256, 0, stream>>>(logits_bf, out, lse, mlp);
    transpose_bf<false><<<dim3(16, 16), 256, 0, stream>>>(Mcur, MT_bf, MEM, DIM, DIM);
    mfma_gemm<2, 2, false, 0, false><<<dim3(128, 4, 1), 256, 0, stream>>>(
        logits_bf, MT_bf, nullptr, nullptr, out + N_DATA, nullptr,
        MEM, MEM, MEM, DIM, 0, 0, 0, 1, 0, 1.0f);
    reduce_loss<<<1, 256, 0, stream>>>(lse, mlp, out + N_DATA + (long)N_DATA * DIM);
}